// Round 1
// baseline (61.677 us; speedup 1.0000x reference)
//
#include <hip/hip_runtime.h>

// Problem constants (fixed-shape bench)
#define BB 2
#define HH 8
#define LL 32
#define CHK 64
#define DD 64
#define MAX_REL 32
#define NN 2048  // LL*CHK

// One block (256 threads) per output row (b,h,q,n).
// Phase 1: compute the 32 per-chunk dot products scores[k] = x_row . emb[b,q,k,:]
// Phase 2: broadcast-write the 2048-float output row (each score repeated 64x).
__global__ __launch_bounds__(256) void relpos_kernel(
    const float* __restrict__ x,      // [B,H,N,D]
    const int*   __restrict__ pos,    // [B,L,L] (int32)
    const float* __restrict__ table,  // [2*MAX_REL+1, D]
    float*       __restrict__ out)    // [B,H,N,N]
{
    const int row = blockIdx.x;            // 0 .. B*H*N-1
    const int n_  = row & (NN - 1);        // index within N
    const int bh  = row >> 11;             // row / N
    const int b   = bh >> 3;               // bh / H
    const int q   = n_ >> 6;               // chunk (row block) index

    const int t    = threadIdx.x;
    const int k    = t >> 3;               // 0..31  (column block)
    const int part = t & 7;                // 0..7   (8 elements of D each)

    // Gathered embedding row for (b,q,k)
    int p = pos[(b * LL + q) * LL + k];
    p = min(max(p, -MAX_REL), MAX_REL) + MAX_REL;

    const float* erow = table + (size_t)p * DD + part * 8;
    const float* xrow = x + (size_t)row * DD + part * 8;

    float4 xa = *(const float4*)(xrow);
    float4 xb = *(const float4*)(xrow + 4);
    float4 ea = *(const float4*)(erow);
    float4 eb = *(const float4*)(erow + 4);

    float s = xa.x * ea.x + xa.y * ea.y + xa.z * ea.z + xa.w * ea.w
            + xb.x * eb.x + xb.y * eb.y + xb.z * eb.z + xb.w * eb.w;

    // Reduce the 8 partials (consecutive lanes) -> full 64-element dot
    s += __shfl_xor(s, 1);
    s += __shfl_xor(s, 2);
    s += __shfl_xor(s, 4);

    __shared__ float sk[32];
    if (part == 0) sk[k] = s;
    __syncthreads();

    // Stream the row out: 2048 floats = 512 float4, 2 per thread, coalesced.
    float4* orow = (float4*)(out + (size_t)row * NN);
    #pragma unroll
    for (int j = 0; j < 2; ++j) {
        int c4 = t + j * 256;              // float4 column index 0..511
        float v = sk[c4 >> 4];             // 16 float4 per 64-float block
        orow[c4] = make_float4(v, v, v, v);
    }
}

extern "C" void kernel_launch(void* const* d_in, const int* in_sizes, int n_in,
                              void* d_out, int out_size, void* d_ws, size_t ws_size,
                              hipStream_t stream) {
    const float* x     = (const float*)d_in[0];
    const int*   pos   = (const int*)d_in[1];
    const float* table = (const float*)d_in[2];
    float*       out   = (float*)d_out;

    dim3 grid(BB * HH * NN);   // 32768 blocks
    relpos_kernel<<<grid, 256, 0, stream>>>(x, pos, table, out);
}

// Round 2
// 54.367 us; speedup vs baseline: 1.1344x; 1.1344x over previous
//
#include <hip/hip_runtime.h>

// Problem constants (fixed-shape bench)
#define BB 2
#define HH 8
#define LL 32
#define CHK 64
#define DD 64
#define MAX_REL 32
#define NN 2048            // LL*CHK
#define RPB 16             // rows per block

// One block (256 threads) per 16 consecutive output rows, all within one
// (b,h,q) chunk-row. Embedding fragments live in registers across all rows.
// Phase 1: 16 rounds of dot products -> sk[r][k] in LDS.
// Phase 2: stream 16 rows x 8 KB = 128 KB of broadcast output, coalesced.
__global__ __launch_bounds__(256) void relpos_kernel(
    const float* __restrict__ x,      // [B,H,N,D]
    const int*   __restrict__ pos,    // [B,L,L]
    const float* __restrict__ table,  // [2*MAX_REL+1, D]
    float*       __restrict__ out)    // [B,H,N,N]
{
    const int blk = blockIdx.x;        // 0 .. B*H*L*4 - 1  (2048)
    const int sub = blk & 3;           // 16-row group within the 64-row chunk
    const int q   = (blk >> 2) & (LL - 1);
    const int bh  = blk >> 7;          // b*H + h
    const int b   = bh >> 3;

    const int t    = threadIdx.x;
    const int k    = t >> 3;           // 0..31  column block
    const int part = t & 7;            // 0..7   8-float slice of D

    // Gather embedding row for (b,q,k) once; keep 8 floats in registers.
    int p = pos[(b * LL + q) * LL + k];
    p = min(max(p, -MAX_REL), MAX_REL) + MAX_REL;
    const float* erow = table + (size_t)p * DD + part * 8;
    const float4 ea = *(const float4*)(erow);
    const float4 eb = *(const float4*)(erow + 4);

    __shared__ float sk[RPB][32];

    const int row0 = (bh << 11) + (q << 6) + (sub << 4); // first global row
    const float* xbase = x + (size_t)row0 * DD + part * 8;

    #pragma unroll 4
    for (int r = 0; r < RPB; ++r) {
        const float4 xa = *(const float4*)(xbase + (size_t)r * DD);
        const float4 xb = *(const float4*)(xbase + (size_t)r * DD + 4);
        float s = xa.x * ea.x + xa.y * ea.y + xa.z * ea.z + xa.w * ea.w
                + xb.x * eb.x + xb.y * eb.y + xb.z * eb.z + xb.w * eb.w;
        s += __shfl_xor(s, 1);
        s += __shfl_xor(s, 2);
        s += __shfl_xor(s, 4);
        if (part == 0) sk[r][k] = s;
    }
    __syncthreads();

    // Phase 2: each thread stores float4 columns t and t+256 of every row.
    const int k0 = t >> 4;                    // 16 float4 per 64-float block
    float4* obase = (float4*)(out + (size_t)row0 * NN);
    #pragma unroll
    for (int r = 0; r < RPB; ++r) {
        const float v0 = sk[r][k0];
        const float v1 = sk[r][16 + k0];
        float4* orow = obase + (size_t)r * (NN / 4);
        orow[t]       = make_float4(v0, v0, v0, v0);
        orow[t + 256] = make_float4(v1, v1, v1, v1);
    }
}

extern "C" void kernel_launch(void* const* d_in, const int* in_sizes, int n_in,
                              void* d_out, int out_size, void* d_ws, size_t ws_size,
                              hipStream_t stream) {
    const float* x     = (const float*)d_in[0];
    const int*   pos   = (const int*)d_in[1];
    const float* table = (const float*)d_in[2];
    float*       out   = (float*)d_out;

    dim3 grid(BB * HH * LL * (CHK / RPB));   // 2048 blocks
    relpos_kernel<<<grid, 256, 0, stream>>>(x, pos, table, out);
}